// Round 11
// baseline (50.612 us; speedup 1.0000x reference)
//
#include <hip/hip_runtime.h>
#include <hip/hip_bf16.h>

// Problem constants
#define HEIGHT 480
#define WIDTH  640
#define IN_CH  6
#define CIN    8      // p, 1-p, 6 features
#define COUT   32
#define BATCH  8
#define NPTS   16384
#define NPTOT  (BATCH * NPTS)          // 131072 = 2^17
// Padded grid: rows 0..482 (point rows 1..481), cols 0..642 (point cols 1..641)
#define GH 483
#define GW 643
#define NCELLS ((size_t)BATCH * GH * GW)   // 2,484,552 cells
#define NWORDS 77644                       // ceil(NCELLS/32)=77643, +1 guard word

// grid layout: [cell][8 x bf16] = one uint4 (16B) per cell.
__device__ __forceinline__ size_t cell_idx(int b, int gy, int gx) {
    return ((size_t)b * GH + gy) * GW + gx;
}

__device__ __forceinline__ void point_cell(const float4 q, int point,
                                           int& b, int& gy, int& gx) {
    gy = (int)rintf(q.z * (float)HEIGHT) + 1;   // padded coord
    gx = (int)rintf(q.y * (float)WIDTH) + 1;
    b  = point >> 14;                           // NPTS = 16384
}

__device__ __forceinline__ unsigned int pack_bf16x2(float a, float b) {
    union { __hip_bfloat162 h; unsigned int u; } cv;
    cv.h = __float22bfloat162_rn(make_float2(a, b));
    return cv.u;
}
__device__ __forceinline__ float bflo(unsigned int u) {
    return __uint_as_float(u << 16);
}
__device__ __forceinline__ float bfhi(unsigned int u) {
    return __uint_as_float(u & 0xffff0000u);
}

// Rare-path: atomic bf16-pair add via u32 CAS loop (multi cells only, ~3%).
__device__ __forceinline__ void cas_add_bf16x2(unsigned int* addr, float a, float b) {
    unsigned int oldv = *addr, assumed;
    do {
        assumed = oldv;
        unsigned int nv = pack_bf16x2(bflo(assumed) + a, bfhi(assumed) + b);
        oldv = atomicCAS(addr, assumed, nv);
    } while (oldv != assumed);
}

// Phase 0: zero both bitmask arrays (2*NWORDS u32 = 621 KB, contiguous).
__global__ void zero_masks_kernel(uint4* __restrict__ m4, int n4) {
    int i = blockIdx.x * blockDim.x + threadIdx.x;
    if (i < n4) m4[i] = make_uint4(0u, 0u, 0u, 0u);
}

// Phase 1: 2 points/thread (split-half -> both coalesced). Per point: set occ
// bit; on collision also set multi bit and zero the 16B grid cell (idempotent;
// value writes happen only in the next dispatch). Two independent atomic
// chains in flight per thread.
__global__ void count_kernel(const float4* __restrict__ xytp,
                             unsigned int* __restrict__ occ,
                             unsigned int* __restrict__ multi,
                             uint4* __restrict__ grid) {
    int t = blockIdx.x * blockDim.x + threadIdx.x;     // 65536 threads exact
    int p0 = t, p1 = t + NPTOT / 2;
    float4 q0 = xytp[p0];
    float4 q1 = xytp[p1];
    int b0, gy0, gx0, b1, gy1, gx1;
    point_cell(q0, p0, b0, gy0, gx0);
    point_cell(q1, p1, b1, gy1, gx1);
    size_t ci0 = cell_idx(b0, gy0, gx0);
    size_t ci1 = cell_idx(b1, gy1, gx1);
    unsigned int w0 = (unsigned int)(ci0 >> 5), bit0 = 1u << (ci0 & 31);
    unsigned int w1 = (unsigned int)(ci1 >> 5), bit1 = 1u << (ci1 & 31);
    unsigned int old0 = atomicOr(&occ[w0], bit0);
    unsigned int old1 = atomicOr(&occ[w1], bit1);
    const uint4 z = make_uint4(0u, 0u, 0u, 0u);
    if (old0 & bit0) { atomicOr(&multi[w0], bit0); grid[ci0] = z; }
    if (old1 & bit1) { atomicOr(&multi[w1], bit1); grid[ci1] = z; }
}

// Phase 2: 2 points/thread. multi clear (~97%) -> one plain 16B store;
// else 4 u32-CAS bf16-pair adds into the zeroed cell.
__global__ void write_kernel(const float4* __restrict__ xytp,
                             const float*  __restrict__ feats,
                             const unsigned int* __restrict__ multi,
                             uint4* __restrict__ grid) {
    int t = blockIdx.x * blockDim.x + threadIdx.x;     // 65536 threads exact
#pragma unroll
    for (int h = 0; h < 2; ++h) {
        int p = t + h * (NPTOT / 2);
        float4 q = xytp[p];
        int b, gy, gx;
        point_cell(q, p, b, gy, gx);
        size_t ci = cell_idx(b, gy, gx);
        const float* f = feats + (size_t)p * IN_CH;
        float f0 = f[0], f1 = f[1], f2 = f[2], f3 = f[3], f4 = f[4], f5 = f[5];
        float v0 = q.w, v1 = 1.0f - q.w;
        unsigned int word = (unsigned int)(ci >> 5);
        unsigned int bit  = 1u << (ci & 31);
        if (!(multi[word] & bit)) {
            grid[ci] = make_uint4(pack_bf16x2(v0, v1), pack_bf16x2(f0, f1),
                                  pack_bf16x2(f2, f3), pack_bf16x2(f4, f5));
        } else {
            unsigned int* cw = (unsigned int*)&grid[ci];
            cas_add_bf16x2(cw + 0, v0, v1);
            cas_add_bf16x2(cw + 1, f0, f1);
            cas_add_bf16x2(cw + 2, f2, f3);
            cas_add_bf16x2(cw + 3, f4, f5);
        }
    }
}

// Phase 3: 2 threads per point splitting the 9 window cells (even k -> sub 0
// incl. the always-occupied center, odd k -> sub 1). Masked uint4 loads issue
// in one batch, then masked FMA pass with bf16 unpack; partials combined via
// __shfl_xor lane^1.
__global__ void __launch_bounds__(256)
conv_gather_kernel(const float4* __restrict__ xytp,
                   const uint4*  __restrict__ grid,
                   const unsigned int* __restrict__ occ,
                   const float*  __restrict__ W,     // [3][3][8][32]
                   const float*  __restrict__ bias,  // [32]
                   float* __restrict__ out) {
    int tid = blockIdx.x * blockDim.x + threadIdx.x;
    if (tid >= NPTOT * 2) return;
    int point = tid >> 1;
    int sub   = tid & 1;                // adjacent lanes share a point

    float4 q = xytp[point];
    int b, gy, gx;
    point_cell(q, point, b, gy, gx);
    size_t center  = cell_idx(b, gy, gx);
    size_t base_ci = center - GW - 1;   // padded window top-left

    // Occupancy bits for the 3x3 window (occ is 310KB -> L2-resident).
    unsigned int occ9 = 0;
#pragma unroll
    for (int ky = 0; ky < 3; ++ky) {
        size_t ci_row = base_ci + (size_t)ky * GW;
        size_t word = ci_row >> 5;
        int sh = (int)(ci_row & 31);
        unsigned long long two =
            (((unsigned long long)occ[word + 1]) << 32) | occ[word];
        occ9 |= ((unsigned int)(two >> sh) & 7u) << (ky * 3);
    }

    // My cells: k with (k&1)==sub. Loads-only masked pass (one latency window).
    uint4 gc[5];
#pragma unroll
    for (int k = 0; k < 9; ++k) {
        if ((k & 1) == sub) {
            if (occ9 & (1u << k)) {
                size_t ci = base_ci + (size_t)(k / 3) * GW + (k % 3);
                gc[k >> 1] = grid[ci];
            }
        }
    }

    // Masked FMA pass over my cells.
    float acc[COUT];
#pragma unroll
    for (int c = 0; c < COUT; ++c) acc[c] = sub ? 0.0f : bias[c];

#pragma unroll
    for (int k = 0; k < 9; ++k) {
        if ((k & 1) == sub) {
            if (occ9 & (1u << k)) {
                uint4 u = gc[k >> 1];
                float gv[CIN] = {bflo(u.x), bfhi(u.x), bflo(u.y), bfhi(u.y),
                                 bflo(u.z), bfhi(u.z), bflo(u.w), bfhi(u.w)};
                const float* wp = W + k * CIN * COUT;
#pragma unroll
                for (int ci2 = 0; ci2 < CIN; ++ci2) {
#pragma unroll
                    for (int c = 0; c < COUT; ++c) {
                        acc[c] = fmaf(gv[ci2], wp[ci2 * COUT + c], acc[c]);
                    }
                }
            }
        }
    }

    // Pair-reduce: compile-time register indices only.
    float res[16];
#pragma unroll
    for (int c = 0; c < 16; ++c) {
        float mine  = sub ? acc[16 + c] : acc[c];
        float other = sub ? acc[c]      : acc[16 + c];
        res[c] = mine + __shfl_xor(other, 1);
    }

    float* o = out + (size_t)point * COUT + sub * 16;
#pragma unroll
    for (int c = 0; c < 16; c += 4) {
        *(float4*)(o + c) = make_float4(res[c], res[c + 1], res[c + 2], res[c + 3]);
    }
}

extern "C" void kernel_launch(void* const* d_in, const int* in_sizes, int n_in,
                              void* d_out, int out_size, void* d_ws, size_t ws_size,
                              hipStream_t stream) {
    const float4* xytp  = (const float4*)d_in[0];   // (8,16384,4)
    const float*  feats = (const float*)d_in[1];    // (8,16384,6)
    const float*  W     = (const float*)d_in[2];    // (3,3,8,32)
    const float*  bias  = (const float*)d_in[3];    // (32,)
    float* out = (float*)d_out;                     // (8,16384,32)

    uint4* grid = (uint4*)d_ws;                     // 39.7 MB (bf16 cells)
    const size_t grid_bytes = NCELLS * 16;
    unsigned int* occ   = (unsigned int*)((char*)d_ws + grid_bytes);
    unsigned int* multi = occ + NWORDS;
    (void)ws_size;

    const int blk = 256;

    const int n4 = (2 * NWORDS) / 4;                // 38,822 uint4
    zero_masks_kernel<<<(n4 + blk - 1) / blk, blk, 0, stream>>>((uint4*)occ, n4);

    count_kernel<<<(NPTOT / 2) / blk, blk, 0, stream>>>(xytp, occ, multi, grid);

    write_kernel<<<(NPTOT / 2) / blk, blk, 0, stream>>>(xytp, feats, multi, grid);

    conv_gather_kernel<<<(NPTOT * 2) / blk, blk, 0, stream>>>(xytp, grid, occ, W, bias, out);
}